// Round 8
// baseline (172.094 us; speedup 1.0000x reference)
//
#include <hip/hip_runtime.h>
#include <stdint.h>

#define N    4096
#define EMB  256
#define NH   4
#define HC   64     // channels per head
#define LOG2E 1.4426950408889634f

typedef __attribute__((ext_vector_type(8))) short s16x8;   // 8 bf16 frag
typedef __attribute__((ext_vector_type(4))) short s16x4;
typedef __attribute__((ext_vector_type(4))) float f32x4;
typedef __attribute__((ext_vector_type(4))) int   i32x4;
typedef unsigned short ushort_t;

__device__ __forceinline__ unsigned short f2bf(float f) {
  unsigned int u = __builtin_bit_cast(unsigned int, f);
  u += 0x7fffu + ((u >> 16) & 1u);      // RNE (finite values only)
  return (unsigned short)(u >> 16);
}

// ---------------- K0: weight transpose only (the sole k1 dependency) ------
__global__ __launch_bounds__(256)
void k0_wprep(const float* __restrict__ W0, ushort_t* __restrict__ WP0,
              const float* __restrict__ W1, ushort_t* __restrict__ WP1)
{
  int b = blockIdx.x;
  int k = b & 255;
  int m = threadIdx.x;
  size_t dst = ((size_t)(k >> 5) * 256 + m) * 32 + (k & 31);
  if (b < 256) WP0[dst] = f2bf(W0[k * EMB + m]);
  else         WP1[dst] = f2bf(W1[k * EMB + m]);
}

// ---------------- KA: merged adj-bitmask scan + K1 GEMM -------------------
// R22: the adj scan (4096 blocks, HBM-streaming, feeds only k34) and k1
// (1024 blocks, MFMA/VALU, feeds k34) have no mutual dependency — only the
// serial stream forced adj->k1 ordering. Merged into one 5120-block kernel
// with interleaved decode (every 4th bid<4096 is a k1 tile) so both block
// types are co-resident on every CU: k1's compute hides inside the adj
// scan's ~10us HBM time. Disjoint outputs (abits vs hS/a_src/a_dst) -> no
// races; numerics identical to the split version.
__global__ __launch_bounds__(256, 4)
void kA_adj_gemm(const int* __restrict__ adj, unsigned int* __restrict__ abits,
                 const float* __restrict__ x,
                 const ushort_t* __restrict__ WlP,   // [8][256][32] k-panels
                 const float* __restrict__ att_src,  // [4][64]
                 const float* __restrict__ att_dst,
                 ushort_t* __restrict__ hS,          // [4][128][64][32]
                 float* __restrict__ a_srcT,         // [4][4096], x log2e
                 float* __restrict__ a_dstT)
{
  __shared__ ushort_t T_lds[64][20];    // [c][node 0..15], stride 20
  __shared__ float red_lds[2][4][16];   // [src/dst][wave][node]

  const int b = blockIdx.x;
  bool is_k1;
  int idx;
  if (b < 4096) {
    is_k1 = (b & 3) == 3;
    idx = is_k1 ? (b >> 2) : ((b >> 2) * 3 + (b & 3));
  } else {
    is_k1 = false;
    idx = 3072 + (b - 4096);
  }

  if (!is_k1) {
    // ---- adj-bitmask path (R11-proven; coalesced 16KB row, shfl merge) ----
    const int i = idx;
    const int t = threadIdx.x;
    const int* src = adj + (size_t)i * N + t * 16;
    i32x4 v0 = *(const i32x4*)(src);
    i32x4 v1 = *(const i32x4*)(src + 4);
    i32x4 v2 = *(const i32x4*)(src + 8);
    i32x4 v3 = *(const i32x4*)(src + 12);
    unsigned int m = 0;
    #pragma unroll
    for (int u = 0; u < 4; ++u) {
      m |= (v0[u] != 0 ? 1u : 0u) << u;
      m |= (v1[u] != 0 ? 1u : 0u) << (4 + u);
      m |= (v2[u] != 0 ? 1u : 0u) << (8 + u);
      m |= (v3[u] != 0 ? 1u : 0u) << (12 + u);
    }
    if ((i >> 4) == t) m |= 1u << (i & 15);        // self-loop
    unsigned int partner = __shfl_xor(m, 1);
    if ((t & 1) == 0) {
      unsigned int word = m | (partner << 16);
      abits[(size_t)(t >> 1) * N + i] = word;
    }
    return;
  }

  // ---- k1 path (R17 structure: 4 waves/SIMD, i-tile 16, col-quarter/wave) --
  const int t = threadIdx.x;
  const int lane = t & 63;
  const int w = t >> 6;                 // col-quarter within head
  const int i0 = (idx & 255) * 16;
  const int head = idx >> 8;
  const int c0 = head * 64;
  const int lq = lane >> 4, lm = lane & 15;

  f32x4 acc = f32x4{0.f, 0.f, 0.f, 0.f};

  const float* xrow = x + (size_t)(i0 + lm) * EMB + lq * 8;
  const ushort_t* wp = WlP + (size_t)(c0 + w * 16 + lm) * 32 + lq * 8;

  #pragma unroll 2
  for (int kp = 0; kp < 8; ++kp) {
    f32x4 v0 = *(const f32x4*)(xrow + kp * 32);
    f32x4 v1 = *(const f32x4*)(xrow + kp * 32 + 4);
    s16x8 a;
    a[0]=(short)f2bf(v0[0]); a[1]=(short)f2bf(v0[1]); a[2]=(short)f2bf(v0[2]); a[3]=(short)f2bf(v0[3]);
    a[4]=(short)f2bf(v1[0]); a[5]=(short)f2bf(v1[1]); a[6]=(short)f2bf(v1[2]); a[7]=(short)f2bf(v1[3]);
    s16x8 bb = *(const s16x8*)(wp + (size_t)kp * 8192);
    acc = __builtin_amdgcn_mfma_f32_16x16x32_bf16(a, bb, acc, 0, 0, 0);
  }

  float ps[4], pd[4];
  {
    int c = w * 16 + lm;
    float wsv = att_src[c0 + c];
    float wdv = att_dst[c0 + c];
    #pragma unroll
    for (int r = 0; r < 4; ++r) {
      float v = acc[r];                 // D: row=lq*4+r, col=lm
      T_lds[c][lq * 4 + r] = f2bf(v);
      ps[r] = v * wsv;
      pd[r] = v * wdv;
    }
  }
  #pragma unroll
  for (int r = 0; r < 4; ++r) {
    #pragma unroll
    for (int mm = 1; mm < 16; mm <<= 1) {
      ps[r] += __shfl_xor(ps[r], mm);
      pd[r] += __shfl_xor(pd[r], mm);
    }
  }
  if (lm == 0) {
    #pragma unroll
    for (int r = 0; r < 4; ++r) {
      int node = lq * 4 + r;
      red_lds[0][w][node] = ps[r];
      red_lds[1][w][node] = pd[r];
    }
  }
  __syncthreads();
  if (t < 16) {
    float s = red_lds[0][0][t] + red_lds[0][1][t] + red_lds[0][2][t] + red_lds[0][3][t];
    float d = red_lds[1][0][t] + red_lds[1][1][t] + red_lds[1][2][t] + red_lds[1][3][t];
    a_srcT[head * N + i0 + t] = s * LOG2E;
    a_dstT[head * N + i0 + t] = d * LOG2E;
  }
  {
    int c = t >> 2, seg = t & 3;        // 64 c x 4 segs of 4 nodes
    s16x4 v = *(const s16x4*)&T_lds[c][seg * 4];
    size_t base = (((size_t)head * 128 + (i0 >> 5)) * 64 + c) * 32
                + (i0 & 16) + seg * 4;
    *(s16x4*)(hS + base) = v;
  }
}

// ---------------- K34: fused masked-softmax attention, atomic-free ---------
// R21: isolated XCD swizzle (won, -1us): head=(bid&7)>>1 -> each XCD serves
// one head; per-XCD L2 set ~3MB < 4MB -> b-frags L2-resident.
// R16/R19 retained: ones-frag denominator, slab epilogue, setprio cluster.
// LDS 67.6KB -> 2 blocks/CU; VGPR ~110 under launch_bounds(512,4)'s cap.
__global__ __launch_bounds__(512, 4)
void k34_attn(const unsigned int* __restrict__ abits, // [128 jw][4096 i]
              const ushort_t* __restrict__ hS,        // [4][128][64][32]
              const float* __restrict__ a_srcT,       // [4][4096], x log2e
              const float* __restrict__ a_dstT,       // [4][4096], x log2e
              const float* __restrict__ bias_att,     // [256]
              ushort_t* __restrict__ oS)              // [256][8][16][32]
{
  __shared__ float acc_lds[8][32][66];     // per-jq partials, stride 66
  __shared__ float l_lds[8][32];

  const int t = threadIdx.x;
  const int lane = t & 63;
  const int jq = t >> 6;           // 0..7 = j-eighth
  const int bid = blockIdx.x;
  const int head = (bid & 7) >> 1;                       // 2 XCDs per head
  const int i0 = (((bid >> 3) << 1) | (bid & 1)) * 32;   // bijective itile
  const int lm = lane & 15, lq = lane >> 4;

  const float* asrc_h = a_srcT + head * N;
  const ushort_t* hS_h = hS + (size_t)head * 128 * 64 * 32;
  float ad[2];
  #pragma unroll
  for (int s = 0; s < 2; ++s) ad[s] = a_dstT[head * N + i0 + s * 16 + lm];

  // bf16 1.0 fragment: B[k][col] = 1 for all 32 k-slots (the 32 j's)
  s16x8 ones;
  #pragma unroll
  for (int u = 0; u < 8; ++u) ones[u] = (short)0x3f80;

  f32x4 acc[2][4];
  f32x4 accl[2];
  #pragma unroll
  for (int s = 0; s < 2; ++s) {
    accl[s] = f32x4{0.f, 0.f, 0.f, 0.f};
    #pragma unroll
    for (int nf = 0; nf < 4; ++nf) acc[s][nf] = f32x4{0.f, 0.f, 0.f, 0.f};
  }

  #pragma unroll 2
  for (int it = 0; it < 16; ++it) {
    const int jw = jq * 16 + it;               // j-window (32 j's)
    const int jl = jw * 32 + lq * 8;           // this lane's first j

    // b-frags first: longest latency, consumed at the END of the body
    const ushort_t* tile = hS_h + (size_t)jw * 2048;     // [64 c][32 j]
    s16x8 b0 = *(const s16x8*)(tile + ( 0 + lm) * 32 + lq * 8);
    s16x8 b1 = *(const s16x8*)(tile + (16 + lm) * 32 + lq * 8);
    s16x8 b2 = *(const s16x8*)(tile + (32 + lm) * 32 + lq * 8);
    s16x8 b3 = *(const s16x8*)(tile + (48 + lm) * 32 + lq * 8);

    unsigned int word[2];
    #pragma unroll
    for (int s = 0; s < 2; ++s)
      word[s] = abits[(size_t)jw * N + i0 + s * 16 + lm];
    f32x4 as0 = *(const f32x4*)(asrc_h + jl);
    f32x4 as1 = *(const f32x4*)(asrc_h + jl + 4);

    #pragma unroll
    for (int s = 0; s < 2; ++s) {
      const unsigned int wsh = word[s] >> (lq * 8);
      unsigned int e[8];
      #pragma unroll
      for (int jj = 0; jj < 8; ++jj) {
        float asv = (jj < 4) ? as0[jj] : as1[jj - 4];
        float sc = asv + ad[s];
        sc = fmaxf(sc, 0.2f * sc);                       // leaky relu (scaled)
        bool con = (wsh >> jj) & 1u;                     // adj + self-loop
        float v = con ? __builtin_amdgcn_exp2f(sc) : 0.f;
        e[jj] = __builtin_bit_cast(unsigned int, v);     // perm takes hi16
      }
      i32x4 pk;
      #pragma unroll
      for (int u = 0; u < 4; ++u)
        pk[u] = (int)__builtin_amdgcn_perm(e[2 * u + 1], e[2 * u], 0x07060302u);
      s16x8 af = __builtin_bit_cast(s16x8, pk);
      __builtin_amdgcn_s_setprio(1);     // favor the MFMA cluster in issue
      acc[s][0] = __builtin_amdgcn_mfma_f32_16x16x32_bf16(af, b0, acc[s][0], 0, 0, 0);
      acc[s][1] = __builtin_amdgcn_mfma_f32_16x16x32_bf16(af, b1, acc[s][1], 0, 0, 0);
      acc[s][2] = __builtin_amdgcn_mfma_f32_16x16x32_bf16(af, b2, acc[s][2], 0, 0, 0);
      acc[s][3] = __builtin_amdgcn_mfma_f32_16x16x32_bf16(af, b3, acc[s][3], 0, 0, 0);
      accl[s]   = __builtin_amdgcn_mfma_f32_16x16x32_bf16(af, ones, accl[s], 0, 0, 0);
      __builtin_amdgcn_s_setprio(0);
    }
  }

  // all 8 waves publish partials; accl[s][r] = row-sum for row lq*4+r
  #pragma unroll
  for (int s = 0; s < 2; ++s)
    #pragma unroll
    for (int nf = 0; nf < 4; ++nf)
      #pragma unroll
      for (int r = 0; r < 4; ++r)
        acc_lds[jq][s * 16 + lq * 4 + r][nf * 16 + lm] = acc[s][nf][r];
  if (lm == 0) {
    #pragma unroll
    for (int s = 0; s < 2; ++s)
      #pragma unroll
      for (int r = 0; r < 4; ++r)
        l_lds[jq][s * 16 + lq * 4 + r] = accl[s][r];
  }
  __syncthreads();

  // parallel reduce: wave jq owns rows jq*4..jq*4+3, lane = column 0..63
  {
    const int c = lane;
    const float bia = bias_att[head * 64 + c];
    const int nf = c >> 4;
    #pragma unroll
    for (int rr = 0; rr < 4; ++rr) {
      const int gr = jq * 4 + rr;          // global row 0..31
      float lsum = l_lds[0][gr];
      #pragma unroll
      for (int q = 1; q < 8; ++q) lsum += l_lds[q][gr];   // broadcast reads
      float v = acc_lds[0][gr][c];
      #pragma unroll
      for (int q = 1; q < 8; ++q) v += acc_lds[q][gr][c]; // conflict-free
      const int s = gr >> 4;
      size_t idx = (((size_t)((i0 >> 4) + s) * 8) + head * 2 + (nf >> 1)) * 512
                 + (gr & 15) * 32 + (nf & 1) * 16 + (c & 15);
      oS[idx] = f2bf(v * (1.f / lsum) + bia);
    }
  }
}

// ---------------- K5: y = oat @ W_out + b_out, then LayerNorm -------------
// R17: 512-thread blocks, 8 waves x 32-col slices, 2 waves/SIMD.
__global__ __launch_bounds__(512, 2)
void k5_gemm_ln(const ushort_t* __restrict__ oS,     // [256][8][16][32]
                const ushort_t* __restrict__ WoP,    // [8][256][32] k-panels
                const float* __restrict__ b_out,
                const float* __restrict__ gamma,
                const float* __restrict__ beta,
                float* __restrict__ out)
{
  __shared__ float y_lds[16][260];
  const int t = threadIdx.x, lane = t & 63, w = t >> 6;   // w = col 32-slice
  const int i0 = blockIdx.x * 16;
  const int lq = lane >> 4, lm = lane & 15;

  f32x4 acc[2];
  acc[0] = f32x4{0.f, 0.f, 0.f, 0.f};
  acc[1] = f32x4{0.f, 0.f, 0.f, 0.f};

  const ushort_t* oS_b = oS + (size_t)(i0 >> 4) * 4096 + lm * 32 + lq * 8;
  const ushort_t* wp0 = WoP + (size_t)(w * 32 +  0 + lm) * 32 + lq * 8;
  const ushort_t* wp1 = WoP + (size_t)(w * 32 + 16 + lm) * 32 + lq * 8;

  #pragma unroll 2
  for (int kp = 0; kp < 8; ++kp) {
    s16x8 a  = *(const s16x8*)(oS_b + (size_t)kp * 512);
    s16x8 b0 = *(const s16x8*)(wp0 + (size_t)kp * 8192);
    s16x8 b1 = *(const s16x8*)(wp1 + (size_t)kp * 8192);
    acc[0] = __builtin_amdgcn_mfma_f32_16x16x32_bf16(a, b0, acc[0], 0, 0, 0);
    acc[1] = __builtin_amdgcn_mfma_f32_16x16x32_bf16(a, b1, acc[1], 0, 0, 0);
  }
  #pragma unroll
  for (int nf = 0; nf < 2; ++nf)
    #pragma unroll
    for (int r = 0; r < 4; ++r) {
      int row = lq * 4 + r;
      int col = w * 32 + nf * 16 + lm;
      y_lds[row][col] = acc[nf][r] + b_out[col];
    }
  __syncthreads();
  f32x4 g  = *(const f32x4*)(gamma + lane * 4);
  f32x4 be = *(const f32x4*)(beta + lane * 4);
  #pragma unroll
  for (int rr = 0; rr < 2; ++rr) {
    int r = w * 2 + rr;
    f32x4 v = *(const f32x4*)&y_lds[r][lane * 4];
    float s1 = v[0] + v[1] + v[2] + v[3];
    float s2 = v[0]*v[0] + v[1]*v[1] + v[2]*v[2] + v[3]*v[3];
    #pragma unroll
    for (int mm = 1; mm < 64; mm <<= 1) { s1 += __shfl_xor(s1, mm); s2 += __shfl_xor(s2, mm); }
    float mu = s1 * (1.f / 256.f);
    float var = s2 * (1.f / 256.f) - mu * mu;
    float rs = rsqrtf(var + 1e-5f);
    f32x4 o;
    #pragma unroll
    for (int u = 0; u < 4; ++u) o[u] = (v[u] - mu) * rs * g[u] + be[u];
    *(f32x4*)(out + (size_t)(i0 + r) * EMB + lane * 4) = o;
  }
}

extern "C" void kernel_launch(void* const* d_in, const int* in_sizes, int n_in,
                              void* d_out, int out_size, void* d_ws, size_t ws_size,
                              hipStream_t stream)
{
  (void)in_sizes; (void)n_in; (void)out_size; (void)ws_size;
  const float* x        = (const float*)d_in[0];
  const int*   adj      = (const int*)d_in[1];
  const float* W_lin    = (const float*)d_in[2];
  const float* att_src  = (const float*)d_in[3];
  const float* att_dst  = (const float*)d_in[4];
  const float* bias_att = (const float*)d_in[5];
  const float* W_out    = (const float*)d_in[6];
  const float* b_out    = (const float*)d_in[7];
  const float* gamma    = (const float*)d_in[8];
  const float* beta     = (const float*)d_in[9];
  float* out = (float*)d_out;

  uint8_t* p = (uint8_t*)d_ws;
  ushort_t* WlP = (ushort_t*)p;  p += (size_t)EMB * EMB * sizeof(ushort_t);
  ushort_t* WoP = (ushort_t*)p;  p += (size_t)EMB * EMB * sizeof(ushort_t);
  ushort_t* hS  = (ushort_t*)p;  p += (size_t)NH * HC * N * sizeof(ushort_t);
  float* a_srcb = (float*)p;     p += (size_t)NH * N * sizeof(float);
  float* a_dstb = (float*)p;     p += (size_t)NH * N * sizeof(float);
  ushort_t* oS  = (ushort_t*)p;  p += (size_t)N * EMB * sizeof(ushort_t);
  unsigned int* abits = (unsigned int*)p; p += (size_t)(N / 32) * N * sizeof(unsigned int);

  k0_wprep<<<512, 256, 0, stream>>>(W_lin, WlP, W_out, WoP);
  kA_adj_gemm<<<4096 + 1024, 256, 0, stream>>>(adj, abits, x, WlP, att_src, att_dst, hS, a_srcb, a_dstb);
  k34_attn<<<(N / 32) * NH, 512, 0, stream>>>(abits, hS, a_srcb, a_dstb, bias_att, oS);
  k5_gemm_ln<<<N / 16, 512, 0, stream>>>(oS, WoP, b_out, gamma, beta, out);
}

// Round 9
// 158.818 us; speedup vs baseline: 1.0836x; 1.0836x over previous
//
#include <hip/hip_runtime.h>
#include <stdint.h>

#define N    4096
#define EMB  256
#define NH   4
#define HC   64     // channels per head
#define LOG2E 1.4426950408889634f

typedef __attribute__((ext_vector_type(8))) short s16x8;   // 8 bf16 frag
typedef __attribute__((ext_vector_type(4))) short s16x4;
typedef __attribute__((ext_vector_type(4))) float f32x4;
typedef __attribute__((ext_vector_type(4))) int   i32x4;
typedef unsigned short ushort_t;

__device__ __forceinline__ unsigned short f2bf(float f) {
  unsigned int u = __builtin_bit_cast(unsigned int, f);
  u += 0x7fffu + ((u >> 16) & 1u);      // RNE (finite values only)
  return (unsigned short)(u >> 16);
}

// ---------------- K_adjprep: adj-bitmask (16 rows/block) + W transpose -----
// R23: R8's counters exposed the old scan's pathology: 4-B abits writes into
// 128 lines spaced 16KB apart -> partial-line RMW (WRITE 16MB vs 2MB ideal,
// RMW fetches), plus only 4 loads/thread of ILP (1.17TB/s, 14.7% peak).
// New: block owns 16 adj rows. Thread t builds 16 masks (16 independent
// 64B load groups -> 16x ILP); after the even/odd shfl merge, even thread
// owns (jw=t>>1, i0..i0+15) and writes ONE FULL 64B line. Writes drop to
// 2MB exact, no RMW; reads get enough in-flight to track the HBM floor.
__global__ __launch_bounds__(256)
void k_adjprep(const int* __restrict__ adj, unsigned int* __restrict__ abits,
               const float* __restrict__ W0, ushort_t* __restrict__ WP0,
               const float* __restrict__ W1, ushort_t* __restrict__ WP1)
{
  int b = blockIdx.x;
  if (b < 256) {
    const int i0 = b * 16;
    const int t = threadIdx.x;
    unsigned int m[16];
    #pragma unroll 4
    for (int r = 0; r < 16; ++r) {
      const int* src = adj + (size_t)(i0 + r) * N + t * 16;
      i32x4 v0 = *(const i32x4*)(src);
      i32x4 v1 = *(const i32x4*)(src + 4);
      i32x4 v2 = *(const i32x4*)(src + 8);
      i32x4 v3 = *(const i32x4*)(src + 12);
      unsigned int mm = 0;
      #pragma unroll
      for (int u = 0; u < 4; ++u) {
        mm |= (v0[u] != 0 ? 1u : 0u) << u;
        mm |= (v1[u] != 0 ? 1u : 0u) << (4 + u);
        mm |= (v2[u] != 0 ? 1u : 0u) << (8 + u);
        mm |= (v3[u] != 0 ? 1u : 0u) << (12 + u);
      }
      if (((i0 + r) >> 4) == t) mm |= 1u << ((i0 + r) & 15);   // self-loop
      m[r] = mm;
    }
    unsigned int w[16];
    #pragma unroll
    for (int r = 0; r < 16; ++r) {
      unsigned int p = __shfl_xor(m[r], 1);
      w[r] = m[r] | (p << 16);            // valid on even t
    }
    if ((t & 1) == 0) {
      unsigned int* dst = abits + (size_t)(t >> 1) * N + i0;   // 64B aligned
      *(i32x4*)(dst)      = i32x4{(int)w[ 0], (int)w[ 1], (int)w[ 2], (int)w[ 3]};
      *(i32x4*)(dst + 4)  = i32x4{(int)w[ 4], (int)w[ 5], (int)w[ 6], (int)w[ 7]};
      *(i32x4*)(dst + 8)  = i32x4{(int)w[ 8], (int)w[ 9], (int)w[10], (int)w[11]};
      *(i32x4*)(dst + 12) = i32x4{(int)w[12], (int)w[13], (int)w[14], (int)w[15]};
    }
  } else {
    b -= 256;
    int k = b & 255;
    int mcol = threadIdx.x;
    size_t dst = ((size_t)(k >> 5) * 256 + mcol) * 32 + (k & 31);
    if (b < 256) WP0[dst] = f2bf(W0[k * EMB + mcol]);
    else         WP1[dst] = f2bf(W1[k * EMB + mcol]);
  }
}

// ---------------- K1: h = x @ W_lin (bf16 MFMA), barrier-free K-loop -------
// R17: 4 waves/SIMD, i-tile 16, one col-quarter per wave. (R8 merge reverted:
// co-residency with the adj scan cost +15us, not saved it.)
__global__ __launch_bounds__(256, 4)
void k1_gemm_h(const float* __restrict__ x,
               const ushort_t* __restrict__ WlP,      // [8][256][32] k-panels
               const float* __restrict__ att_src,     // [4][64]
               const float* __restrict__ att_dst,
               ushort_t* __restrict__ hS,             // [4][128][64][32]
               float* __restrict__ a_srcT,            // [4][4096], x log2e
               float* __restrict__ a_dstT)
{
  __shared__ ushort_t T_lds[64][20];    // [c][node 0..15], stride 20
  __shared__ float red_lds[2][4][16];   // [src/dst][wave][node]
  const int t = threadIdx.x;
  const int lane = t & 63;
  const int w = t >> 6;                 // col-quarter within head
  const int i0 = blockIdx.x * 16;
  const int head = blockIdx.y;
  const int c0 = head * 64;
  const int lq = lane >> 4, lm = lane & 15;

  f32x4 acc = f32x4{0.f, 0.f, 0.f, 0.f};

  const float* xrow = x + (size_t)(i0 + lm) * EMB + lq * 8;
  const ushort_t* wp = WlP + (size_t)(c0 + w * 16 + lm) * 32 + lq * 8;

  #pragma unroll 2
  for (int kp = 0; kp < 8; ++kp) {
    f32x4 v0 = *(const f32x4*)(xrow + kp * 32);
    f32x4 v1 = *(const f32x4*)(xrow + kp * 32 + 4);
    s16x8 a;
    a[0]=(short)f2bf(v0[0]); a[1]=(short)f2bf(v0[1]); a[2]=(short)f2bf(v0[2]); a[3]=(short)f2bf(v0[3]);
    a[4]=(short)f2bf(v1[0]); a[5]=(short)f2bf(v1[1]); a[6]=(short)f2bf(v1[2]); a[7]=(short)f2bf(v1[3]);
    s16x8 bb = *(const s16x8*)(wp + (size_t)kp * 8192);
    acc = __builtin_amdgcn_mfma_f32_16x16x32_bf16(a, bb, acc, 0, 0, 0);
  }

  float ps[4], pd[4];
  {
    int c = w * 16 + lm;
    float wsv = att_src[c0 + c];
    float wdv = att_dst[c0 + c];
    #pragma unroll
    for (int r = 0; r < 4; ++r) {
      float v = acc[r];                 // D: row=lq*4+r, col=lm
      T_lds[c][lq * 4 + r] = f2bf(v);
      ps[r] = v * wsv;
      pd[r] = v * wdv;
    }
  }
  #pragma unroll
  for (int r = 0; r < 4; ++r) {
    #pragma unroll
    for (int mm = 1; mm < 16; mm <<= 1) {
      ps[r] += __shfl_xor(ps[r], mm);
      pd[r] += __shfl_xor(pd[r], mm);
    }
  }
  if (lm == 0) {
    #pragma unroll
    for (int r = 0; r < 4; ++r) {
      int node = lq * 4 + r;
      red_lds[0][w][node] = ps[r];
      red_lds[1][w][node] = pd[r];
    }
  }
  __syncthreads();
  if (t < 16) {
    float s = red_lds[0][0][t] + red_lds[0][1][t] + red_lds[0][2][t] + red_lds[0][3][t];
    float d = red_lds[1][0][t] + red_lds[1][1][t] + red_lds[1][2][t] + red_lds[1][3][t];
    a_srcT[head * N + i0 + t] = s * LOG2E;
    a_dstT[head * N + i0 + t] = d * LOG2E;
  }
  {
    int c = t >> 2, seg = t & 3;        // 64 c x 4 segs of 4 nodes
    s16x4 v = *(const s16x4*)&T_lds[c][seg * 4];
    size_t base = (((size_t)head * 128 + (i0 >> 5)) * 64 + c) * 32
                + (i0 & 16) + seg * 4;
    *(s16x4*)(hS + base) = v;
  }
}

// ---------------- K34: fused masked-softmax attention, atomic-free ---------
// R21: isolated XCD swizzle (won, -1us): head=(bid&7)>>1 -> each XCD serves
// one head; per-XCD L2 set ~3MB < 4MB -> b-frags L2-resident.
// R16/R19 retained: ones-frag denominator, slab epilogue, setprio cluster.
// LDS 67.6KB -> 2 blocks/CU; VGPR ~110 under launch_bounds(512,4)'s cap.
__global__ __launch_bounds__(512, 4)
void k34_attn(const unsigned int* __restrict__ abits, // [128 jw][4096 i]
              const ushort_t* __restrict__ hS,        // [4][128][64][32]
              const float* __restrict__ a_srcT,       // [4][4096], x log2e
              const float* __restrict__ a_dstT,       // [4][4096], x log2e
              const float* __restrict__ bias_att,     // [256]
              ushort_t* __restrict__ oS)              // [256][8][16][32]
{
  __shared__ float acc_lds[8][32][66];     // per-jq partials, stride 66
  __shared__ float l_lds[8][32];

  const int t = threadIdx.x;
  const int lane = t & 63;
  const int jq = t >> 6;           // 0..7 = j-eighth
  const int bid = blockIdx.x;
  const int head = (bid & 7) >> 1;                       // 2 XCDs per head
  const int i0 = (((bid >> 3) << 1) | (bid & 1)) * 32;   // bijective itile
  const int lm = lane & 15, lq = lane >> 4;

  const float* asrc_h = a_srcT + head * N;
  const ushort_t* hS_h = hS + (size_t)head * 128 * 64 * 32;
  float ad[2];
  #pragma unroll
  for (int s = 0; s < 2; ++s) ad[s] = a_dstT[head * N + i0 + s * 16 + lm];

  // bf16 1.0 fragment: B[k][col] = 1 for all 32 k-slots (the 32 j's)
  s16x8 ones;
  #pragma unroll
  for (int u = 0; u < 8; ++u) ones[u] = (short)0x3f80;

  f32x4 acc[2][4];
  f32x4 accl[2];
  #pragma unroll
  for (int s = 0; s < 2; ++s) {
    accl[s] = f32x4{0.f, 0.f, 0.f, 0.f};
    #pragma unroll
    for (int nf = 0; nf < 4; ++nf) acc[s][nf] = f32x4{0.f, 0.f, 0.f, 0.f};
  }

  #pragma unroll 2
  for (int it = 0; it < 16; ++it) {
    const int jw = jq * 16 + it;               // j-window (32 j's)
    const int jl = jw * 32 + lq * 8;           // this lane's first j

    // b-frags first: longest latency, consumed at the END of the body
    const ushort_t* tile = hS_h + (size_t)jw * 2048;     // [64 c][32 j]
    s16x8 b0 = *(const s16x8*)(tile + ( 0 + lm) * 32 + lq * 8);
    s16x8 b1 = *(const s16x8*)(tile + (16 + lm) * 32 + lq * 8);
    s16x8 b2 = *(const s16x8*)(tile + (32 + lm) * 32 + lq * 8);
    s16x8 b3 = *(const s16x8*)(tile + (48 + lm) * 32 + lq * 8);

    unsigned int word[2];
    #pragma unroll
    for (int s = 0; s < 2; ++s)
      word[s] = abits[(size_t)jw * N + i0 + s * 16 + lm];
    f32x4 as0 = *(const f32x4*)(asrc_h + jl);
    f32x4 as1 = *(const f32x4*)(asrc_h + jl + 4);

    #pragma unroll
    for (int s = 0; s < 2; ++s) {
      const unsigned int wsh = word[s] >> (lq * 8);
      unsigned int e[8];
      #pragma unroll
      for (int jj = 0; jj < 8; ++jj) {
        float asv = (jj < 4) ? as0[jj] : as1[jj - 4];
        float sc = asv + ad[s];
        sc = fmaxf(sc, 0.2f * sc);                       // leaky relu (scaled)
        bool con = (wsh >> jj) & 1u;                     // adj + self-loop
        float v = con ? __builtin_amdgcn_exp2f(sc) : 0.f;
        e[jj] = __builtin_bit_cast(unsigned int, v);     // perm takes hi16
      }
      i32x4 pk;
      #pragma unroll
      for (int u = 0; u < 4; ++u)
        pk[u] = (int)__builtin_amdgcn_perm(e[2 * u + 1], e[2 * u], 0x07060302u);
      s16x8 af = __builtin_bit_cast(s16x8, pk);
      __builtin_amdgcn_s_setprio(1);     // favor the MFMA cluster in issue
      acc[s][0] = __builtin_amdgcn_mfma_f32_16x16x32_bf16(af, b0, acc[s][0], 0, 0, 0);
      acc[s][1] = __builtin_amdgcn_mfma_f32_16x16x32_bf16(af, b1, acc[s][1], 0, 0, 0);
      acc[s][2] = __builtin_amdgcn_mfma_f32_16x16x32_bf16(af, b2, acc[s][2], 0, 0, 0);
      acc[s][3] = __builtin_amdgcn_mfma_f32_16x16x32_bf16(af, b3, acc[s][3], 0, 0, 0);
      accl[s]   = __builtin_amdgcn_mfma_f32_16x16x32_bf16(af, ones, accl[s], 0, 0, 0);
      __builtin_amdgcn_s_setprio(0);
    }
  }

  // all 8 waves publish partials; accl[s][r] = row-sum for row lq*4+r
  #pragma unroll
  for (int s = 0; s < 2; ++s)
    #pragma unroll
    for (int nf = 0; nf < 4; ++nf)
      #pragma unroll
      for (int r = 0; r < 4; ++r)
        acc_lds[jq][s * 16 + lq * 4 + r][nf * 16 + lm] = acc[s][nf][r];
  if (lm == 0) {
    #pragma unroll
    for (int s = 0; s < 2; ++s)
      #pragma unroll
      for (int r = 0; r < 4; ++r)
        l_lds[jq][s * 16 + lq * 4 + r] = accl[s][r];
  }
  __syncthreads();

  // parallel reduce: wave jq owns rows jq*4..jq*4+3, lane = column 0..63
  {
    const int c = lane;
    const float bia = bias_att[head * 64 + c];
    const int nf = c >> 4;
    #pragma unroll
    for (int rr = 0; rr < 4; ++rr) {
      const int gr = jq * 4 + rr;          // global row 0..31
      float lsum = l_lds[0][gr];
      #pragma unroll
      for (int q = 1; q < 8; ++q) lsum += l_lds[q][gr];   // broadcast reads
      float v = acc_lds[0][gr][c];
      #pragma unroll
      for (int q = 1; q < 8; ++q) v += acc_lds[q][gr][c]; // conflict-free
      const int s = gr >> 4;
      size_t idx = (((size_t)((i0 >> 4) + s) * 8) + head * 2 + (nf >> 1)) * 512
                 + (gr & 15) * 32 + (nf & 1) * 16 + (c & 15);
      oS[idx] = f2bf(v * (1.f / lsum) + bia);
    }
  }
}

// ---------------- K5: y = oat @ W_out + b_out, then LayerNorm -------------
// R17: 512-thread blocks, 8 waves x 32-col slices, 2 waves/SIMD.
__global__ __launch_bounds__(512, 2)
void k5_gemm_ln(const ushort_t* __restrict__ oS,     // [256][8][16][32]
                const ushort_t* __restrict__ WoP,    // [8][256][32] k-panels
                const float* __restrict__ b_out,
                const float* __restrict__ gamma,
                const float* __restrict__ beta,
                float* __restrict__ out)
{
  __shared__ float y_lds[16][260];
  const int t = threadIdx.x, lane = t & 63, w = t >> 6;   // w = col 32-slice
  const int i0 = blockIdx.x * 16;
  const int lq = lane >> 4, lm = lane & 15;

  f32x4 acc[2];
  acc[0] = f32x4{0.f, 0.f, 0.f, 0.f};
  acc[1] = f32x4{0.f, 0.f, 0.f, 0.f};

  const ushort_t* oS_b = oS + (size_t)(i0 >> 4) * 4096 + lm * 32 + lq * 8;
  const ushort_t* wp0 = WoP + (size_t)(w * 32 +  0 + lm) * 32 + lq * 8;
  const ushort_t* wp1 = WoP + (size_t)(w * 32 + 16 + lm) * 32 + lq * 8;

  #pragma unroll 2
  for (int kp = 0; kp < 8; ++kp) {
    s16x8 a  = *(const s16x8*)(oS_b + (size_t)kp * 512);
    s16x8 b0 = *(const s16x8*)(wp0 + (size_t)kp * 8192);
    s16x8 b1 = *(const s16x8*)(wp1 + (size_t)kp * 8192);
    acc[0] = __builtin_amdgcn_mfma_f32_16x16x32_bf16(a, b0, acc[0], 0, 0, 0);
    acc[1] = __builtin_amdgcn_mfma_f32_16x16x32_bf16(a, b1, acc[1], 0, 0, 0);
  }
  #pragma unroll
  for (int nf = 0; nf < 2; ++nf)
    #pragma unroll
    for (int r = 0; r < 4; ++r) {
      int row = lq * 4 + r;
      int col = w * 32 + nf * 16 + lm;
      y_lds[row][col] = acc[nf][r] + b_out[col];
    }
  __syncthreads();
  f32x4 g  = *(const f32x4*)(gamma + lane * 4);
  f32x4 be = *(const f32x4*)(beta + lane * 4);
  #pragma unroll
  for (int rr = 0; rr < 2; ++rr) {
    int r = w * 2 + rr;
    f32x4 v = *(const f32x4*)&y_lds[r][lane * 4];
    float s1 = v[0] + v[1] + v[2] + v[3];
    float s2 = v[0]*v[0] + v[1]*v[1] + v[2]*v[2] + v[3]*v[3];
    #pragma unroll
    for (int mm = 1; mm < 64; mm <<= 1) { s1 += __shfl_xor(s1, mm); s2 += __shfl_xor(s2, mm); }
    float mu = s1 * (1.f / 256.f);
    float var = s2 * (1.f / 256.f) - mu * mu;
    float rs = rsqrtf(var + 1e-5f);
    f32x4 o;
    #pragma unroll
    for (int u = 0; u < 4; ++u) o[u] = (v[u] - mu) * rs * g[u] + be[u];
    *(f32x4*)(out + (size_t)(i0 + r) * EMB + lane * 4) = o;
  }
}

extern "C" void kernel_launch(void* const* d_in, const int* in_sizes, int n_in,
                              void* d_out, int out_size, void* d_ws, size_t ws_size,
                              hipStream_t stream)
{
  (void)in_sizes; (void)n_in; (void)out_size; (void)ws_size;
  const float* x        = (const float*)d_in[0];
  const int*   adj      = (const int*)d_in[1];
  const float* W_lin    = (const float*)d_in[2];
  const float* att_src  = (const float*)d_in[3];
  const float* att_dst  = (const float*)d_in[4];
  const float* bias_att = (const float*)d_in[5];
  const float* W_out    = (const float*)d_in[6];
  const float* b_out    = (const float*)d_in[7];
  const float* gamma    = (const float*)d_in[8];
  const float* beta     = (const float*)d_in[9];
  float* out = (float*)d_out;

  uint8_t* p = (uint8_t*)d_ws;
  ushort_t* WlP = (ushort_t*)p;  p += (size_t)EMB * EMB * sizeof(ushort_t);
  ushort_t* WoP = (ushort_t*)p;  p += (size_t)EMB * EMB * sizeof(ushort_t);
  ushort_t* hS  = (ushort_t*)p;  p += (size_t)NH * HC * N * sizeof(ushort_t);
  float* a_srcb = (float*)p;     p += (size_t)NH * N * sizeof(float);
  float* a_dstb = (float*)p;     p += (size_t)NH * N * sizeof(float);
  ushort_t* oS  = (ushort_t*)p;  p += (size_t)N * EMB * sizeof(ushort_t);
  unsigned int* abits = (unsigned int*)p; p += (size_t)(N / 32) * N * sizeof(unsigned int);

  k_adjprep<<<256 + 512, 256, 0, stream>>>(adj, abits, W_lin, WlP, W_out, WoP);
  k1_gemm_h<<<dim3(N / 16, NH), 256, 0, stream>>>(x, WlP, att_src, att_dst, hS, a_srcb, a_dstb);
  k34_attn<<<(N / 32) * NH, 512, 0, stream>>>(abits, hS, a_srcb, a_dstb, bias_att, oS);
  k5_gemm_ln<<<N / 16, 512, 0, stream>>>(oS, WoP, b_out, gamma, beta, out);
}

// Round 10
// 156.235 us; speedup vs baseline: 1.1015x; 1.0165x over previous
//
#include <hip/hip_runtime.h>
#include <stdint.h>

#define N    4096
#define EMB  256
#define NH   4
#define HC   64     // channels per head
#define LOG2E 1.4426950408889634f

typedef __attribute__((ext_vector_type(8))) short s16x8;   // 8 bf16 frag
typedef __attribute__((ext_vector_type(4))) short s16x4;
typedef __attribute__((ext_vector_type(4))) float f32x4;
typedef __attribute__((ext_vector_type(4))) int   i32x4;
typedef unsigned short ushort_t;

__device__ __forceinline__ unsigned short f2bf(float f) {
  unsigned int u = __builtin_bit_cast(unsigned int, f);
  u += 0x7fffu + ((u >> 16) & 1u);      // RNE (finite values only)
  return (unsigned short)(u >> 16);
}

// ---------------- K_prep: fused adj-bitmask + weight-transpose -------------
// R24: restored to the R11/R6-proven form (one block per adj row, coalesced
// 16KB row read, shfl merge, scattered 4B writes). The R23 full-line rewrite
// measured +1.8us worse: the scattered stores from 128 consecutive blocks on
// the same XCD write-combine in L2; the R8 "write amplification" was a
// merge-induced artifact, not a property of this standalone kernel.
__global__ __launch_bounds__(256)
void k_prep(const float* __restrict__ W0, ushort_t* __restrict__ WP0,
            const float* __restrict__ W1, ushort_t* __restrict__ WP1,
            const int* __restrict__ adj, unsigned int* __restrict__ abits)
{
  int b = blockIdx.x;
  if (b < 4096) {
    const int i = b;
    const int t = threadIdx.x;
    const int* src = adj + (size_t)i * N + t * 16;
    i32x4 v0 = *(const i32x4*)(src);
    i32x4 v1 = *(const i32x4*)(src + 4);
    i32x4 v2 = *(const i32x4*)(src + 8);
    i32x4 v3 = *(const i32x4*)(src + 12);
    unsigned int m = 0;
    #pragma unroll
    for (int u = 0; u < 4; ++u) {
      m |= (v0[u] != 0 ? 1u : 0u) << u;
      m |= (v1[u] != 0 ? 1u : 0u) << (4 + u);
      m |= (v2[u] != 0 ? 1u : 0u) << (8 + u);
      m |= (v3[u] != 0 ? 1u : 0u) << (12 + u);
    }
    if ((i >> 4) == t) m |= 1u << (i & 15);        // self-loop
    unsigned int partner = __shfl_xor(m, 1);
    if ((t & 1) == 0) {
      unsigned int word = m | (partner << 16);
      abits[(size_t)(t >> 1) * N + i] = word;
    }
  } else {
    b -= 4096;
    int k = b & 255;
    int m = threadIdx.x;
    size_t dst = ((size_t)(k >> 5) * 256 + m) * 32 + (k & 31);
    if (b < 256) WP0[dst] = f2bf(W0[k * EMB + m]);
    else         WP1[dst] = f2bf(W1[k * EMB + m]);
  }
}

// ---------------- K1: h = x @ W_lin (bf16 MFMA), barrier-free K-loop -------
// R17: 4 waves/SIMD, i-tile 16, one col-quarter per wave.
__global__ __launch_bounds__(256, 4)
void k1_gemm_h(const float* __restrict__ x,
               const ushort_t* __restrict__ WlP,      // [8][256][32] k-panels
               const float* __restrict__ att_src,     // [4][64]
               const float* __restrict__ att_dst,
               ushort_t* __restrict__ hS,             // [4][128][64][32]
               float* __restrict__ a_srcT,            // [4][4096], x log2e
               float* __restrict__ a_dstT)
{
  __shared__ ushort_t T_lds[64][20];    // [c][node 0..15], stride 20
  __shared__ float red_lds[2][4][16];   // [src/dst][wave][node]
  const int t = threadIdx.x;
  const int lane = t & 63;
  const int w = t >> 6;                 // col-quarter within head
  const int i0 = blockIdx.x * 16;
  const int head = blockIdx.y;
  const int c0 = head * 64;
  const int lq = lane >> 4, lm = lane & 15;

  f32x4 acc = f32x4{0.f, 0.f, 0.f, 0.f};

  const float* xrow = x + (size_t)(i0 + lm) * EMB + lq * 8;
  const ushort_t* wp = WlP + (size_t)(c0 + w * 16 + lm) * 32 + lq * 8;

  #pragma unroll 2
  for (int kp = 0; kp < 8; ++kp) {
    f32x4 v0 = *(const f32x4*)(xrow + kp * 32);
    f32x4 v1 = *(const f32x4*)(xrow + kp * 32 + 4);
    s16x8 a;
    a[0]=(short)f2bf(v0[0]); a[1]=(short)f2bf(v0[1]); a[2]=(short)f2bf(v0[2]); a[3]=(short)f2bf(v0[3]);
    a[4]=(short)f2bf(v1[0]); a[5]=(short)f2bf(v1[1]); a[6]=(short)f2bf(v1[2]); a[7]=(short)f2bf(v1[3]);
    s16x8 bb = *(const s16x8*)(wp + (size_t)kp * 8192);
    acc = __builtin_amdgcn_mfma_f32_16x16x32_bf16(a, bb, acc, 0, 0, 0);
  }

  float ps[4], pd[4];
  {
    int c = w * 16 + lm;
    float wsv = att_src[c0 + c];
    float wdv = att_dst[c0 + c];
    #pragma unroll
    for (int r = 0; r < 4; ++r) {
      float v = acc[r];                 // D: row=lq*4+r, col=lm
      T_lds[c][lq * 4 + r] = f2bf(v);
      ps[r] = v * wsv;
      pd[r] = v * wdv;
    }
  }
  #pragma unroll
  for (int r = 0; r < 4; ++r) {
    #pragma unroll
    for (int mm = 1; mm < 16; mm <<= 1) {
      ps[r] += __shfl_xor(ps[r], mm);
      pd[r] += __shfl_xor(pd[r], mm);
    }
  }
  if (lm == 0) {
    #pragma unroll
    for (int r = 0; r < 4; ++r) {
      int node = lq * 4 + r;
      red_lds[0][w][node] = ps[r];
      red_lds[1][w][node] = pd[r];
    }
  }
  __syncthreads();
  if (t < 16) {
    float s = red_lds[0][0][t] + red_lds[0][1][t] + red_lds[0][2][t] + red_lds[0][3][t];
    float d = red_lds[1][0][t] + red_lds[1][1][t] + red_lds[1][2][t] + red_lds[1][3][t];
    a_srcT[head * N + i0 + t] = s * LOG2E;
    a_dstT[head * N + i0 + t] = d * LOG2E;
  }
  {
    int c = t >> 2, seg = t & 3;        // 64 c x 4 segs of 4 nodes
    s16x4 v = *(const s16x4*)&T_lds[c][seg * 4];
    size_t base = (((size_t)head * 128 + (i0 >> 5)) * 64 + c) * 32
                + (i0 & 16) + seg * 4;
    *(s16x4*)(hS + base) = v;
  }
}

// ---------------- K34: fused masked-softmax attention, atomic-free ---------
// R21: isolated XCD swizzle (won, -1us): head=(bid&7)>>1 -> each XCD serves
// one head; per-XCD L2 set ~3MB < 4MB -> b-frags L2-resident.
// R16/R19 retained: ones-frag denominator, slab epilogue, setprio cluster.
// LDS 67.6KB -> 2 blocks/CU; VGPR ~110 under launch_bounds(512,4)'s cap.
__global__ __launch_bounds__(512, 4)
void k34_attn(const unsigned int* __restrict__ abits, // [128 jw][4096 i]
              const ushort_t* __restrict__ hS,        // [4][128][64][32]
              const float* __restrict__ a_srcT,       // [4][4096], x log2e
              const float* __restrict__ a_dstT,       // [4][4096], x log2e
              const float* __restrict__ bias_att,     // [256]
              ushort_t* __restrict__ oS)              // [256][8][16][32]
{
  __shared__ float acc_lds[8][32][66];     // per-jq partials, stride 66
  __shared__ float l_lds[8][32];

  const int t = threadIdx.x;
  const int lane = t & 63;
  const int jq = t >> 6;           // 0..7 = j-eighth
  const int bid = blockIdx.x;
  const int head = (bid & 7) >> 1;                       // 2 XCDs per head
  const int i0 = (((bid >> 3) << 1) | (bid & 1)) * 32;   // bijective itile
  const int lm = lane & 15, lq = lane >> 4;

  const float* asrc_h = a_srcT + head * N;
  const ushort_t* hS_h = hS + (size_t)head * 128 * 64 * 32;
  float ad[2];
  #pragma unroll
  for (int s = 0; s < 2; ++s) ad[s] = a_dstT[head * N + i0 + s * 16 + lm];

  // bf16 1.0 fragment: B[k][col] = 1 for all 32 k-slots (the 32 j's)
  s16x8 ones;
  #pragma unroll
  for (int u = 0; u < 8; ++u) ones[u] = (short)0x3f80;

  f32x4 acc[2][4];
  f32x4 accl[2];
  #pragma unroll
  for (int s = 0; s < 2; ++s) {
    accl[s] = f32x4{0.f, 0.f, 0.f, 0.f};
    #pragma unroll
    for (int nf = 0; nf < 4; ++nf) acc[s][nf] = f32x4{0.f, 0.f, 0.f, 0.f};
  }

  #pragma unroll 2
  for (int it = 0; it < 16; ++it) {
    const int jw = jq * 16 + it;               // j-window (32 j's)
    const int jl = jw * 32 + lq * 8;           // this lane's first j

    // b-frags first: longest latency, consumed at the END of the body
    const ushort_t* tile = hS_h + (size_t)jw * 2048;     // [64 c][32 j]
    s16x8 b0 = *(const s16x8*)(tile + ( 0 + lm) * 32 + lq * 8);
    s16x8 b1 = *(const s16x8*)(tile + (16 + lm) * 32 + lq * 8);
    s16x8 b2 = *(const s16x8*)(tile + (32 + lm) * 32 + lq * 8);
    s16x8 b3 = *(const s16x8*)(tile + (48 + lm) * 32 + lq * 8);

    unsigned int word[2];
    #pragma unroll
    for (int s = 0; s < 2; ++s)
      word[s] = abits[(size_t)jw * N + i0 + s * 16 + lm];
    f32x4 as0 = *(const f32x4*)(asrc_h + jl);
    f32x4 as1 = *(const f32x4*)(asrc_h + jl + 4);

    #pragma unroll
    for (int s = 0; s < 2; ++s) {
      const unsigned int wsh = word[s] >> (lq * 8);
      unsigned int e[8];
      #pragma unroll
      for (int jj = 0; jj < 8; ++jj) {
        float asv = (jj < 4) ? as0[jj] : as1[jj - 4];
        float sc = asv + ad[s];
        sc = fmaxf(sc, 0.2f * sc);                       // leaky relu (scaled)
        bool con = (wsh >> jj) & 1u;                     // adj + self-loop
        float v = con ? __builtin_amdgcn_exp2f(sc) : 0.f;
        e[jj] = __builtin_bit_cast(unsigned int, v);     // perm takes hi16
      }
      i32x4 pk;
      #pragma unroll
      for (int u = 0; u < 4; ++u)
        pk[u] = (int)__builtin_amdgcn_perm(e[2 * u + 1], e[2 * u], 0x07060302u);
      s16x8 af = __builtin_bit_cast(s16x8, pk);
      __builtin_amdgcn_s_setprio(1);     // favor the MFMA cluster in issue
      acc[s][0] = __builtin_amdgcn_mfma_f32_16x16x32_bf16(af, b0, acc[s][0], 0, 0, 0);
      acc[s][1] = __builtin_amdgcn_mfma_f32_16x16x32_bf16(af, b1, acc[s][1], 0, 0, 0);
      acc[s][2] = __builtin_amdgcn_mfma_f32_16x16x32_bf16(af, b2, acc[s][2], 0, 0, 0);
      acc[s][3] = __builtin_amdgcn_mfma_f32_16x16x32_bf16(af, b3, acc[s][3], 0, 0, 0);
      accl[s]   = __builtin_amdgcn_mfma_f32_16x16x32_bf16(af, ones, accl[s], 0, 0, 0);
      __builtin_amdgcn_s_setprio(0);
    }
  }

  // all 8 waves publish partials; accl[s][r] = row-sum for row lq*4+r
  #pragma unroll
  for (int s = 0; s < 2; ++s)
    #pragma unroll
    for (int nf = 0; nf < 4; ++nf)
      #pragma unroll
      for (int r = 0; r < 4; ++r)
        acc_lds[jq][s * 16 + lq * 4 + r][nf * 16 + lm] = acc[s][nf][r];
  if (lm == 0) {
    #pragma unroll
    for (int s = 0; s < 2; ++s)
      #pragma unroll
      for (int r = 0; r < 4; ++r)
        l_lds[jq][s * 16 + lq * 4 + r] = accl[s][r];
  }
  __syncthreads();

  // parallel reduce: wave jq owns rows jq*4..jq*4+3, lane = column 0..63
  {
    const int c = lane;
    const float bia = bias_att[head * 64 + c];
    const int nf = c >> 4;
    #pragma unroll
    for (int rr = 0; rr < 4; ++rr) {
      const int gr = jq * 4 + rr;          // global row 0..31
      float lsum = l_lds[0][gr];
      #pragma unroll
      for (int q = 1; q < 8; ++q) lsum += l_lds[q][gr];   // broadcast reads
      float v = acc_lds[0][gr][c];
      #pragma unroll
      for (int q = 1; q < 8; ++q) v += acc_lds[q][gr][c]; // conflict-free
      const int s = gr >> 4;
      size_t idx = (((size_t)((i0 >> 4) + s) * 8) + head * 2 + (nf >> 1)) * 512
                 + (gr & 15) * 32 + (nf & 1) * 16 + (c & 15);
      oS[idx] = f2bf(v * (1.f / lsum) + bia);
    }
  }
}

// ---------------- K5: y = oat @ W_out + b_out, then LayerNorm -------------
// R17: 512-thread blocks, 8 waves x 32-col slices, 2 waves/SIMD.
__global__ __launch_bounds__(512, 2)
void k5_gemm_ln(const ushort_t* __restrict__ oS,     // [256][8][16][32]
                const ushort_t* __restrict__ WoP,    // [8][256][32] k-panels
                const float* __restrict__ b_out,
                const float* __restrict__ gamma,
                const float* __restrict__ beta,
                float* __restrict__ out)
{
  __shared__ float y_lds[16][260];
  const int t = threadIdx.x, lane = t & 63, w = t >> 6;   // w = col 32-slice
  const int i0 = blockIdx.x * 16;
  const int lq = lane >> 4, lm = lane & 15;

  f32x4 acc[2];
  acc[0] = f32x4{0.f, 0.f, 0.f, 0.f};
  acc[1] = f32x4{0.f, 0.f, 0.f, 0.f};

  const ushort_t* oS_b = oS + (size_t)(i0 >> 4) * 4096 + lm * 32 + lq * 8;
  const ushort_t* wp0 = WoP + (size_t)(w * 32 +  0 + lm) * 32 + lq * 8;
  const ushort_t* wp1 = WoP + (size_t)(w * 32 + 16 + lm) * 32 + lq * 8;

  #pragma unroll 2
  for (int kp = 0; kp < 8; ++kp) {
    s16x8 a  = *(const s16x8*)(oS_b + (size_t)kp * 512);
    s16x8 b0 = *(const s16x8*)(wp0 + (size_t)kp * 8192);
    s16x8 b1 = *(const s16x8*)(wp1 + (size_t)kp * 8192);
    acc[0] = __builtin_amdgcn_mfma_f32_16x16x32_bf16(a, b0, acc[0], 0, 0, 0);
    acc[1] = __builtin_amdgcn_mfma_f32_16x16x32_bf16(a, b1, acc[1], 0, 0, 0);
  }
  #pragma unroll
  for (int nf = 0; nf < 2; ++nf)
    #pragma unroll
    for (int r = 0; r < 4; ++r) {
      int row = lq * 4 + r;
      int col = w * 32 + nf * 16 + lm;
      y_lds[row][col] = acc[nf][r] + b_out[col];
    }
  __syncthreads();
  f32x4 g  = *(const f32x4*)(gamma + lane * 4);
  f32x4 be = *(const f32x4*)(beta + lane * 4);
  #pragma unroll
  for (int rr = 0; rr < 2; ++rr) {
    int r = w * 2 + rr;
    f32x4 v = *(const f32x4*)&y_lds[r][lane * 4];
    float s1 = v[0] + v[1] + v[2] + v[3];
    float s2 = v[0]*v[0] + v[1]*v[1] + v[2]*v[2] + v[3]*v[3];
    #pragma unroll
    for (int mm = 1; mm < 64; mm <<= 1) { s1 += __shfl_xor(s1, mm); s2 += __shfl_xor(s2, mm); }
    float mu = s1 * (1.f / 256.f);
    float var = s2 * (1.f / 256.f) - mu * mu;
    float rs = rsqrtf(var + 1e-5f);
    f32x4 o;
    #pragma unroll
    for (int u = 0; u < 4; ++u) o[u] = (v[u] - mu) * rs * g[u] + be[u];
    *(f32x4*)(out + (size_t)(i0 + r) * EMB + lane * 4) = o;
  }
}

extern "C" void kernel_launch(void* const* d_in, const int* in_sizes, int n_in,
                              void* d_out, int out_size, void* d_ws, size_t ws_size,
                              hipStream_t stream)
{
  (void)in_sizes; (void)n_in; (void)out_size; (void)ws_size;
  const float* x        = (const float*)d_in[0];
  const int*   adj      = (const int*)d_in[1];
  const float* W_lin    = (const float*)d_in[2];
  const float* att_src  = (const float*)d_in[3];
  const float* att_dst  = (const float*)d_in[4];
  const float* bias_att = (const float*)d_in[5];
  const float* W_out    = (const float*)d_in[6];
  const float* b_out    = (const float*)d_in[7];
  const float* gamma    = (const float*)d_in[8];
  const float* beta     = (const float*)d_in[9];
  float* out = (float*)d_out;

  uint8_t* p = (uint8_t*)d_ws;
  ushort_t* WlP = (ushort_t*)p;  p += (size_t)EMB * EMB * sizeof(ushort_t);
  ushort_t* WoP = (ushort_t*)p;  p += (size_t)EMB * EMB * sizeof(ushort_t);
  ushort_t* hS  = (ushort_t*)p;  p += (size_t)NH * HC * N * sizeof(ushort_t);
  float* a_srcb = (float*)p;     p += (size_t)NH * N * sizeof(float);
  float* a_dstb = (float*)p;     p += (size_t)NH * N * sizeof(float);
  ushort_t* oS  = (ushort_t*)p;  p += (size_t)N * EMB * sizeof(ushort_t);
  unsigned int* abits = (unsigned int*)p; p += (size_t)(N / 32) * N * sizeof(unsigned int);

  k_prep<<<4096 + 512, 256, 0, stream>>>(W_lin, WlP, W_out, WoP, adj, abits);
  k1_gemm_h<<<dim3(N / 16, NH), 256, 0, stream>>>(x, WlP, att_src, att_dst, hS, a_srcb, a_dstb);
  k34_attn<<<(N / 32) * NH, 512, 0, stream>>>(abits, hS, a_srcb, a_dstb, bias_att, oS);
  k5_gemm_ln<<<N / 16, 512, 0, stream>>>(oS, WoP, b_out, gamma, beta, out);
}